// Round 1
// baseline (240.938 us; speedup 1.0000x reference)
//
#include <hip/hip_runtime.h>
#include <math.h>

#define NB 128     // B
#define NN_ 116    // N
#define NK 4       // K
#define NF 72      // F
#define NS 8       // S
#define TOPK 10

#define BK (NB*NK)            // 512
#define BN (NB*NN_)           // 14848
#define NN2 (NN_*NN_)         // 13456
#define KN (NK*NN_)           // 464
#define ROWS (BK*NN_)         // 59392

// output section offsets (floats)
#define OFF_UNI 0
#define SZ_UNI (NB*KN*KN)                 // 27557888
#define OFF_NF (OFF_UNI + SZ_UNI)
#define SZ_NF (NB*KN*NF)                  // 4276224
#define OFF_GF (OFF_NF + SZ_NF)
#define SZ_GF (NB*128)
#define OFF_IA (OFF_GF + SZ_GF)
#define SZ_IA (NB*NK*NN_*NN_)             // 6889472
#define OFF_IE (OFF_IA + SZ_IA)
#define SZ_IE (NB*NN_*NK*NK)              // 237568
#define OFF_SP (OFF_IE + SZ_IE)

// scratch inside the unified region (floats, relative to uni base)
#define SCR_SC 0                          // ROWS*N (sc, then intra in-place)
#define SCR_H  (SZ_IA)                    // ROWS*64
#define SCR_DEG (SCR_H + ROWS*64)
#define SCR_CLUS (SCR_DEG + ROWS)
#define SCR_DENS (SCR_CLUS + ROWS)
#define SCR_STREN (SCR_DENS + BN)
#define SCR_GFV (SCR_STREN + BN)          // NB*150
#define SCR_AUX (SCR_GFV + NB*150)        // 2*NB

__device__ __forceinline__ float sigmoidf_(float x){ return 1.0f/(1.0f+expf(-x)); }
#define CLIP1(x) fminf(1.0f, fmaxf(-1.0f, (x)))

// ---------------- K1: intra correlation + masks -> sc ----------------
__global__ __launch_bounds__(256) void k_intra_corr(const float* __restrict__ band,
    const float* __restrict__ thadj, float* __restrict__ sc_out)
{
    __shared__ float sx[NF*120];          // sx[f*120+n]
    __shared__ float smu[NN_], sstd[NN_];
    __shared__ float scorr[NN2];
    __shared__ unsigned skm[NN_*4];
    int bk = blockIdx.x;
    int b = bk >> 2, k = bk & 3;
    int t = threadIdx.x;
    const float* xin = band + ((size_t)b*NN_*NK + k)*NF;
    for (int e = t; e < NN_*NF; e += 256){
        int n = e / NF, f = e - n*NF;
        sx[f*120 + n] = xin[(size_t)n*NK*NF + f];
    }
    __syncthreads();
    if (t < NN_){
        float s = 0.f, ss = 0.f;
        for (int f = 0; f < NF; ++f){ float v = sx[f*120+t]; s += v; ss += v*v; }
        float mu = s * (1.0f/NF);
        smu[t] = mu;
        sstd[t] = sqrtf(fmaxf(ss - s*mu, 1e-8f));
    }
    __syncthreads();
    for (int tt = t; tt < 29*29; tt += 256){
        int ti = tt / 29, tj = tt - ti*29;
        int i0 = ti*4, j0 = tj*4;
        float acc[4][4] = {};
        for (int f = 0; f < NF; ++f){
            const float4 a = *(const float4*)&sx[f*120 + i0];
            const float4 c = *(const float4*)&sx[f*120 + j0];
            float av[4] = {a.x,a.y,a.z,a.w};
            float cv[4] = {c.x,c.y,c.z,c.w};
            #pragma unroll
            for (int r = 0; r < 4; ++r)
                #pragma unroll
                for (int cc = 0; cc < 4; ++cc)
                    acc[r][cc] = fmaf(av[r], cv[cc], acc[r][cc]);
        }
        #pragma unroll
        for (int r = 0; r < 4; ++r){
            float mi = smu[i0+r], si = sstd[i0+r];
            #pragma unroll
            for (int cc = 0; cc < 4; ++cc){
                float cov = acc[r][cc] - (float)NF * mi * smu[j0+cc];
                float corr = cov / (si * sstd[j0+cc] + 1e-8f);
                scorr[(i0+r)*NN_ + j0 + cc] = CLIP1(corr);
            }
        }
    }
    __syncthreads();
    if (t < NN_){
        float tv[TOPK]; int tix[TOPK];
        #pragma unroll
        for (int p = 0; p < TOPK; ++p){ tv[p] = -1.0f; tix[p] = 0; }
        for (int j = 0; j < NN_; ++j){
            float cv = fabsf(scorr[t*NN_+j]); int ci = j;
            #pragma unroll
            for (int p = 0; p < TOPK; ++p){
                bool gt = cv > tv[p];
                float nv = gt ? cv : tv[p]; int ni = gt ? ci : tix[p];
                float ov = gt ? tv[p] : cv; int oi = gt ? tix[p] : ci;
                tv[p] = nv; tix[p] = ni; cv = ov; ci = oi;
            }
        }
        unsigned m0=0,m1=0,m2=0,m3=0;
        #pragma unroll
        for (int p = 0; p < TOPK; ++p){
            int j = tix[p];
            unsigned bit = 1u << (j & 31);
            int w = j >> 5;
            if (w == 0) m0 |= bit; else if (w == 1) m1 |= bit; else if (w == 2) m2 |= bit; else m3 |= bit;
        }
        skm[t*4+0]=m0; skm[t*4+1]=m1; skm[t*4+2]=m2; skm[t*4+3]=m3;
    }
    __syncthreads();
    float th = 0.1f + sigmoidf_(thadj[0]) * 0.2f;
    float* dst = sc_out + (size_t)bk * NN2;
    for (int e = t; e < NN2; e += 256){
        int i = e / NN_, j = e - i*NN_;
        float cij = scorr[e];
        float cji = scorr[j*NN_ + i];
        bool kij = (skm[i*4 + (j>>5)] >> (j&31)) & 1u;
        bool kji = (skm[j*4 + (i>>5)] >> (i&31)) & 1u;
        float mij = (fabsf(cij) > th && kij) ? cij : 0.0f;
        float mji = (fabsf(cji) > th && kji) ? cji : 0.0f;
        dst[e] = fmaxf(0.5f*(mij+mji), 0.0f);
    }
}

// ---------------- K2a: H = relu(sc @ W1^T + b1) ----------------
#define RB2A 32
__global__ __launch_bounds__(256) void k_mlp1(const float* __restrict__ sc,
    const float* __restrict__ W1, const float* __restrict__ b1, float* __restrict__ H)
{
    __shared__ float sW[64*117];
    __shared__ float sb[64];
    __shared__ float srow[RB2A*NN_];
    int t = threadIdx.x;
    for (int e = t; e < 64*NN_; e += 256){ int o = e / NN_, j = e - o*NN_; sW[o*117+j] = W1[e]; }
    if (t < 64) sb[t] = b1[t];
    int r0 = blockIdx.x * RB2A;
    for (int e = t; e < RB2A*NN_; e += 256) srow[e] = sc[(size_t)r0*NN_ + e];
    __syncthreads();
    int o = t & 63, g = t >> 6;
    const float* rp = &srow[g*8*NN_];
    float acc[8] = {};
    for (int j = 0; j < NN_; ++j){
        float w = sW[o*117+j];
        #pragma unroll
        for (int m = 0; m < 8; ++m)
            acc[m] = fmaf(rp[m*NN_ + j], w, acc[m]);
    }
    float bo = sb[o];
    #pragma unroll
    for (int m = 0; m < 8; ++m)
        H[(size_t)(r0 + g*8 + m)*64 + o] = fmaxf(acc[m] + bo, 0.0f);
}

// ---------------- K2b: intra = sigmoid(H @ W2^T + b2), in-place over sc ----------------
#define RB2B 32
__global__ __launch_bounds__(256) void k_mlp2(const float* __restrict__ Hbuf,
    const float* __restrict__ W2, const float* __restrict__ b2, float* __restrict__ intra)
{
    __shared__ float sW[NN_*65];
    __shared__ float sb[NN_];
    __shared__ float sH[RB2B*64];
    int t = threadIdx.x;
    for (int e = t; e < NN_*64; e += 256){ int j = e >> 6, o = e & 63; sW[j*65+o] = W2[e]; }
    if (t < NN_) sb[t] = b2[t];
    int r0 = blockIdx.x * RB2B;
    for (int e = t; e < RB2B*64; e += 256) sH[e] = Hbuf[(size_t)r0*64 + e];
    __syncthreads();
    for (int task = t; task < NN_*8; task += 256){
        int rg = task / NN_, j = task - rg*NN_;
        float acc[4] = {};
        const float* hp = &sH[rg*4*64];
        for (int o = 0; o < 64; ++o){
            float w = sW[j*65+o];
            #pragma unroll
            for (int m = 0; m < 4; ++m)
                acc[m] = fmaf(hp[m*64 + o], w, acc[m]);
        }
        float bj = sb[j];
        #pragma unroll
        for (int m = 0; m < 4; ++m)
            intra[((size_t)r0 + rg*4 + m)*NN_ + j] = sigmoidf_(acc[m] + bj);
    }
}

// ---------------- K3: intra_adj = sym(intra); deg/clus ----------------
__global__ __launch_bounds__(256) void k_sym_intra(const float* __restrict__ intra,
    float* __restrict__ intra_adj, float* __restrict__ deg_out, float* __restrict__ clus_out)
{
    __shared__ float sm[NN2];
    int bk = blockIdx.x, t = threadIdx.x;
    const float* src = intra + (size_t)bk*NN2;
    for (int e = t; e < NN2; e += 256) sm[e] = src[e];
    __syncthreads();
    float* dst = intra_adj + (size_t)bk*NN2;
    for (int e = t; e < NN2; e += 256){
        int i = e / NN_, j = e - i*NN_;
        dst[e] = 0.5f*(sm[e] + sm[j*NN_ + i]);
    }
    if (t < NN_){
        float tri = 0.f; int dg = 0;
        for (int j = 0; j < NN_; ++j){
            float v = 0.5f*(sm[t*NN_+j] + sm[j*NN_+t]);
            tri = fmaf(v, v, tri);
            dg += (v > 0.f) ? 1 : 0;
        }
        float d = (float)dg;
        deg_out[(size_t)bk*NN_ + t] = d;
        clus_out[(size_t)bk*NN_ + t] = tri / (d*d + 1e-8f);
    }
}

// ---------------- K4: inter branch, fully fused ----------------
__global__ __launch_bounds__(256) void k_inter(const float* __restrict__ band,
    const float* __restrict__ attn, const float* __restrict__ thadj2,
    const float* __restrict__ fwp,
    const float* __restrict__ W1, const float* __restrict__ b1,
    const float* __restrict__ W2, const float* __restrict__ b2,
    float* __restrict__ inter_out, float* __restrict__ dens_out, float* __restrict__ stren_out)
{
    __shared__ float sW1[128], sb1[32], sW2[128], sb2[4];
    __shared__ float sMat[256*4];
    int t = threadIdx.x;
    if (t < 128) sW1[t] = W1[t];
    if (t < 32) sb1[t] = b1[t];
    if (t >= 128 && t < 256) sW2[t-128] = W2[t-128];
    if (t < 4) sb2[t] = b2[t];
    __syncthreads();
    int l = t & 3;
    int il = t >> 2;
    size_t item = (size_t)blockIdx.x*64 + il;

    const float* xr = band + item*(NK*NF) + l*NF;
    float s=0,p0=0,p1=0,p2=0,p3=0;
    for (int f = 0; f < NF; ++f){
        float v = xr[f];
        float v1=__shfl_xor(v,1), v2=__shfl_xor(v,2), v3=__shfl_xor(v,3);
        s += v; p0=fmaf(v,v,p0); p1=fmaf(v,v1,p1); p2=fmaf(v,v2,p2); p3=fmaf(v,v3,p3);
    }
    float mu = s*(1.0f/NF);
    float mu1=__shfl_xor(mu,1), mu2=__shfl_xor(mu,2), mu3=__shfl_xor(mu,3);
    float sd = sqrtf(fmaxf(p0 - s*mu, 1e-8f));
    float sd1=__shfl_xor(sd,1), sd2=__shfl_xor(sd,2), sd3=__shfl_xor(sd,3);
    float c0 = CLIP1((p0 - (float)NF*mu*mu )/(sd*sd +1e-8f));
    float c1 = CLIP1((p1 - (float)NF*mu*mu1)/(sd*sd1+1e-8f));
    float c2 = CLIP1((p2 - (float)NF*mu*mu2)/(sd*sd2+1e-8f));
    float c3 = CLIP1((p3 - (float)NF*mu*mu3)/(sd*sd3+1e-8f));

    const float* ar = attn + item*(NS*NK) + l;
    float as=0,q0=0,q1=0,q2=0,q3=0;
    #pragma unroll
    for (int s8 = 0; s8 < NS; ++s8){
        float v = ar[s8*NK];
        float v1=__shfl_xor(v,1), v2=__shfl_xor(v,2), v3=__shfl_xor(v,3);
        as += v; q0=fmaf(v,v,q0); q1=fmaf(v,v1,q1); q2=fmaf(v,v2,q2); q3=fmaf(v,v3,q3);
    }
    float am = as*(1.0f/NS);
    float am1=__shfl_xor(am,1), am2=__shfl_xor(am,2), am3=__shfl_xor(am,3);
    float ad = sqrtf(fmaxf(q0 - as*am, 1e-8f));
    float ad1=__shfl_xor(ad,1), ad2=__shfl_xor(ad,2), ad3=__shfl_xor(ad,3);
    float a0 = CLIP1((q0 - (float)NS*am*am )/(ad*ad +1e-8f));
    float a1 = CLIP1((q1 - (float)NS*am*am1)/(ad*ad1+1e-8f));
    float a2 = CLIP1((q2 - (float)NS*am*am2)/(ad*ad2+1e-8f));
    float a3 = CLIP1((q3 - (float)NS*am*am3)/(ad*ad3+1e-8f));

    float fwv = sigmoidf_(fwp[0]);
    float g0 = fwv*c0 + (1.0f-fwv)*a0;
    float g1 = fwv*c1 + (1.0f-fwv)*a1;
    float g2 = fwv*c2 + (1.0f-fwv)*a2;
    float g3 = fwv*c3 + (1.0f-fwv)*a3;
    float th2 = 0.2f + sigmoidf_(thadj2[0])*0.2f;
    float m0 = (fabsf(g0)>th2)?g0:0.f;
    float m1 = (fabsf(g1)>th2)?g1:0.f;
    float m2 = (fabsf(g2)>th2)?g2:0.f;
    float m3 = (fabsf(g3)>th2)?g3:0.f;

    // write masked matrix row-major (cols via XOR slot), then symmetrize
    sMat[il*16 + l*4 + (l^0)] = m0;
    sMat[il*16 + l*4 + (l^1)] = m1;
    sMat[il*16 + l*4 + (l^2)] = m2;
    sMat[il*16 + l*4 + (l^3)] = m3;
    __syncthreads();
    float x0 = fmaxf(0.5f*(sMat[il*16 + l*4 + 0] + sMat[il*16 + 0*4 + l]), 0.f);
    float x1 = fmaxf(0.5f*(sMat[il*16 + l*4 + 1] + sMat[il*16 + 1*4 + l]), 0.f);
    float x2 = fmaxf(0.5f*(sMat[il*16 + l*4 + 2] + sMat[il*16 + 2*4 + l]), 0.f);
    float x3 = fmaxf(0.5f*(sMat[il*16 + l*4 + 3] + sMat[il*16 + 3*4 + l]), 0.f);

    float h[32];
    #pragma unroll
    for (int o = 0; o < 32; ++o){
        float acc = sb1[o];
        acc = fmaf(sW1[o*4+0], x0, acc);
        acc = fmaf(sW1[o*4+1], x1, acc);
        acc = fmaf(sW1[o*4+2], x2, acc);
        acc = fmaf(sW1[o*4+3], x3, acc);
        h[o] = fmaxf(acc, 0.f);
    }
    float o0=sb2[0], o1=sb2[1], o2=sb2[2], o3=sb2[3];
    #pragma unroll
    for (int o = 0; o < 32; ++o){
        float hv = h[o];
        o0 = fmaf(sW2[0*32+o], hv, o0);
        o1 = fmaf(sW2[1*32+o], hv, o1);
        o2 = fmaf(sW2[2*32+o], hv, o2);
        o3 = fmaf(sW2[3*32+o], hv, o3);
    }
    o0 = sigmoidf_(o0); o1 = sigmoidf_(o1); o2 = sigmoidf_(o2); o3 = sigmoidf_(o3);
    __syncthreads();
    sMat[il*16 + l*4 + 0] = o0;
    sMat[il*16 + l*4 + 1] = o1;
    sMat[il*16 + l*4 + 2] = o2;
    sMat[il*16 + l*4 + 3] = o3;
    __syncthreads();
    float y0 = 0.5f*(o0 + sMat[il*16 + 0*4 + l]);
    float y1 = 0.5f*(o1 + sMat[il*16 + 1*4 + l]);
    float y2 = 0.5f*(o2 + sMat[il*16 + 2*4 + l]);
    float y3 = 0.5f*(o3 + sMat[il*16 + 3*4 + l]);
    *(float4*)&inter_out[item*16 + l*4] = make_float4(y0,y1,y2,y3);

    float cnt = ((y0>0.f)?1.f:0.f) + ((y1>0.f)?1.f:0.f) + ((y2>0.f)?1.f:0.f) + ((y3>0.f)?1.f:0.f);
    float sum = y0+y1+y2+y3;
    cnt += __shfl_xor(cnt,1); cnt += __shfl_xor(cnt,2);
    sum += __shfl_xor(sum,1); sum += __shfl_xor(sum,2);
    if (l == 0){
        dens_out[item]  = cnt * (1.0f/16.0f);
        stren_out[item] = sum * (1.0f/16.0f);
    }
}

// ---------------- node features transpose-copy ----------------
__global__ __launch_bounds__(256) void k_nodefeat(const float* __restrict__ band, float* __restrict__ nf)
{
    const int total4 = NB*KN*NF/4;
    for (int x4 = blockIdx.x*blockDim.x + threadIdx.x; x4 < total4; x4 += gridDim.x*blockDim.x){
        int x = x4*4;
        int f = x % NF;
        int rest = x / NF;
        int n = rest % NN_;
        int rest2 = rest / NN_;
        int k = rest2 & 3;
        int b = rest2 >> 2;
        float4 v = *(const float4*)&band[(((size_t)b*NN_ + n)*NK + k)*NF + f];
        *(float4*)&nf[x] = v;
    }
}

// ---------------- per-(b,f) mean/std ----------------
__global__ __launch_bounds__(64) void k_meanstd(const float* __restrict__ band, float* __restrict__ gf)
{
    int bf = blockIdx.x; int b = bf / NF, f = bf - b*NF;
    int t = threadIdx.x;
    float s = 0.f, ss = 0.f;
    for (int nk = t; nk < NN_*NK; nk += 64){
        float v = band[(size_t)b*(NN_*NK*NF) + (size_t)nk*NF + f];
        s += v; ss += v*v;
    }
    #pragma unroll
    for (int d = 1; d < 64; d <<= 1){ s += __shfl_xor(s,d); ss += __shfl_xor(ss,d); }
    if (t == 0){
        const float M = (float)(NN_*NK);
        float mean = s / M;
        float var = fmaxf((ss - s*mean)/(M - 1.0f), 0.0f);
        gf[(size_t)b*150 + f] = mean;
        gf[(size_t)b*150 + NF + f] = sqrtf(var);
    }
}

// ---------------- per-b graph stats ----------------
__global__ __launch_bounds__(256) void k_graphstats(const float* __restrict__ deg,
    const float* __restrict__ clus, const float* __restrict__ dens,
    const float* __restrict__ stren, float* __restrict__ gf, float* __restrict__ aux)
{
    int b = blockIdx.x, t = threadIdx.x;
    __shared__ float sA[4], sB[4];

    float s = 0.f, ss = 0.f;
    for (int e = t; e < KN; e += 256){ float v = deg[(size_t)b*KN + e]; s += v; ss += v*v; }
    #pragma unroll
    for (int d = 1; d < 64; d <<= 1){ s += __shfl_xor(s,d); ss += __shfl_xor(ss,d); }
    if ((t & 63) == 0){ sA[t>>6] = s; sB[t>>6] = ss; }
    __syncthreads();
    if (t == 0){
        float S0 = sA[0]+sA[1]+sA[2]+sA[3], S1 = sB[0]+sB[1]+sB[2]+sB[3];
        float Mv = (float)KN, mean = S0/Mv;
        float var = fmaxf((S1 - S0*mean)/(Mv - 1.0f), 0.0f);
        gf[(size_t)b*150 + 144] = mean;
        gf[(size_t)b*150 + 145] = sqrtf(var);
        aux[b] = S0;
    }
    __syncthreads();

    s = 0.f; ss = 0.f;
    for (int e = t; e < KN; e += 256){ float v = clus[(size_t)b*KN + e]; s += v; ss += v*v; }
    #pragma unroll
    for (int d = 1; d < 64; d <<= 1){ s += __shfl_xor(s,d); ss += __shfl_xor(ss,d); }
    if ((t & 63) == 0){ sA[t>>6] = s; sB[t>>6] = ss; }
    __syncthreads();
    if (t == 0){
        float S0 = sA[0]+sA[1]+sA[2]+sA[3], S1 = sB[0]+sB[1]+sB[2]+sB[3];
        float Mv = (float)KN, mean = S0/Mv;
        float var = fmaxf((S1 - S0*mean)/(Mv - 1.0f), 0.0f);
        gf[(size_t)b*150 + 146] = mean;
        gf[(size_t)b*150 + 147] = sqrtf(var);
    }
    __syncthreads();

    s = 0.f; ss = 0.f;
    for (int e = t; e < NN_; e += 256){ s += dens[(size_t)b*NN_ + e]; ss += stren[(size_t)b*NN_ + e]; }
    #pragma unroll
    for (int d = 1; d < 64; d <<= 1){ s += __shfl_xor(s,d); ss += __shfl_xor(ss,d); }
    if ((t & 63) == 0){ sA[t>>6] = s; sB[t>>6] = ss; }
    __syncthreads();
    if (t == 0){
        float S0 = sA[0]+sA[1]+sA[2]+sA[3], S1 = sB[0]+sB[1]+sB[2]+sB[3];
        gf[(size_t)b*150 + 148] = S0 / (float)NN_;
        gf[(size_t)b*150 + 149] = S1 / (float)NN_;
        aux[128 + b] = S0 * 16.0f;
    }
}

// ---------------- graph linear ----------------
__global__ __launch_bounds__(256) void k_graphlin(const float* __restrict__ gf,
    const float* __restrict__ Wc, const float* __restrict__ bc, float* __restrict__ outp)
{
    int id = blockIdx.x*blockDim.x + threadIdx.x;
    if (id >= NB*128) return;
    int b = id >> 7, o = id & 127;
    float acc = bc[o];
    const float* g = gf + (size_t)b*150;
    const float* w = Wc + (size_t)o*150;
    for (int c = 0; c < 150; ++c) acc = fmaf(g[c], w[c], acc);
    outp[id] = fmaxf(acc, 0.f);
}

// ---------------- sparsity scalars ----------------
__global__ __launch_bounds__(128) void k_sparsity(const float* __restrict__ aux, float* __restrict__ out3)
{
    int t = threadIdx.x;
    float a = aux[t];
    float c = aux[128 + t];
    #pragma unroll
    for (int d = 1; d < 64; d <<= 1){ a += __shfl_xor(a,d); c += __shfl_xor(c,d); }
    __shared__ float sA[2], sC[2];
    if ((t & 63) == 0){ sA[t>>6] = a; sC[t>>6] = c; }
    __syncthreads();
    if (t == 0){
        float icnt = sA[0]+sA[1], jcnt = sC[0]+sC[1];
        const float it = 6889472.0f, jt = 237568.0f;
        float isp = 1.0f - icnt/it;
        float jsp = 1.0f - jcnt/jt;
        out3[0] = isp; out3[1] = jsp;
        out3[2] = (isp*it + jsp*jt)/(it + jt);
    }
}

// ---------------- unified assembly (runs LAST) ----------------
__global__ __launch_bounds__(128) void k_unified(const float* __restrict__ intra_adj,
    const float* __restrict__ inter_adj, float* __restrict__ uni)
{
    int row = blockIdx.x;                  // b*464 + p
    int b = row / KN, p = row - b*KN;
    int k1 = p / NN_, i = p - k1*NN_;
    int t = threadIdx.x;
    if (t >= NN_) return;
    int q0 = t*4;
    int k2 = t / 29;
    int j0 = q0 - k2*NN_;
    float4 v;
    if (k2 == k1){
        v = *(const float4*)&intra_adj[(((size_t)b*NK + k1)*NN_ + i)*NN_ + j0];
    } else {
        int d = i - j0;
        float val = 0.f;
        if (d >= 0 && d < 4)
            val = inter_adj[(((size_t)b*NN_ + i)*NK + k1)*NK + k2];
        v.x = (d==0)?val:0.f;
        v.y = (d==1)?val:0.f;
        v.z = (d==2)?val:0.f;
        v.w = (d==3)?val:0.f;
    }
    *(float4*)&uni[(size_t)row*KN + q0] = v;
}

extern "C" void kernel_launch(void* const* d_in, const int* in_sizes, int n_in,
                              void* d_out, int out_size, void* d_ws, size_t ws_size,
                              hipStream_t stream)
{
    const float* band = (const float*)d_in[0];
    const float* attn = (const float*)d_in[1];
    const float* thA  = (const float*)d_in[2];
    const float* thE  = (const float*)d_in[3];
    const float* fw   = (const float*)d_in[4];
    const float* iW1  = (const float*)d_in[5];
    const float* ib1  = (const float*)d_in[6];
    const float* iW2  = (const float*)d_in[7];
    const float* ib2  = (const float*)d_in[8];
    const float* eW1  = (const float*)d_in[9];
    const float* eb1  = (const float*)d_in[10];
    const float* eW2  = (const float*)d_in[11];
    const float* eb2  = (const float*)d_in[12];
    const float* cW   = (const float*)d_in[13];
    const float* cb   = (const float*)d_in[14];

    float* out = (float*)d_out;
    float* uni = out + OFF_UNI;
    float* nf  = out + OFF_NF;
    float* gfo = out + OFF_GF;
    float* ia  = out + OFF_IA;
    float* ie  = out + OFF_IE;
    float* sp  = out + OFF_SP;

    float* scr_sc    = uni + SCR_SC;
    float* scr_H     = uni + SCR_H;
    float* scr_deg   = uni + SCR_DEG;
    float* scr_clus  = uni + SCR_CLUS;
    float* scr_dens  = uni + SCR_DENS;
    float* scr_stren = uni + SCR_STREN;
    float* scr_gf    = uni + SCR_GFV;
    float* scr_aux   = uni + SCR_AUX;

    k_intra_corr<<<BK, 256, 0, stream>>>(band, thA, scr_sc);
    k_mlp1<<<ROWS/RB2A, 256, 0, stream>>>(scr_sc, iW1, ib1, scr_H);
    k_mlp2<<<ROWS/RB2B, 256, 0, stream>>>(scr_H, iW2, ib2, scr_sc);
    k_sym_intra<<<BK, 256, 0, stream>>>(scr_sc, ia, scr_deg, scr_clus);
    k_inter<<<BN/64, 256, 0, stream>>>(band, attn, thE, fw, eW1, eb1, eW2, eb2,
                                       ie, scr_dens, scr_stren);
    k_nodefeat<<<2048, 256, 0, stream>>>(band, nf);
    k_meanstd<<<NB*NF, 64, 0, stream>>>(band, scr_gf);
    k_graphstats<<<NB, 256, 0, stream>>>(scr_deg, scr_clus, scr_dens, scr_stren, scr_gf, scr_aux);
    k_graphlin<<<64, 256, 0, stream>>>(scr_gf, cW, cb, gfo);
    k_sparsity<<<1, 128, 0, stream>>>(scr_aux, sp);
    k_unified<<<NB*KN, 128, 0, stream>>>(ia, ie, uni);
}

// Round 2
// 215.992 us; speedup vs baseline: 1.1155x; 1.1155x over previous
//
#include <hip/hip_runtime.h>
#include <math.h>

#define NB 128     // B
#define NN_ 116    // N
#define NK 4       // K
#define NF 72      // F
#define NS 8       // S
#define TOPK 10

#define BK (NB*NK)            // 512
#define BN (NB*NN_)           // 14848
#define NN2 (NN_*NN_)         // 13456
#define KN (NK*NN_)           // 464
#define ROWS (BK*NN_)         // 59392
#define LROW 117              // padded LDS row stride (odd -> conflict-free transpose)

// output section offsets (floats)
#define OFF_UNI 0
#define SZ_UNI (NB*KN*KN)                 // 27557888
#define OFF_NF (OFF_UNI + SZ_UNI)
#define SZ_NF (NB*KN*NF)                  // 4276224
#define OFF_GF (OFF_NF + SZ_NF)
#define SZ_GF (NB*128)
#define OFF_IA (OFF_GF + SZ_GF)
#define SZ_IA (NB*NK*NN_*NN_)             // 6889472
#define OFF_IE (OFF_IA + SZ_IA)
#define SZ_IE (NB*NN_*NK*NK)              // 237568
#define OFF_SP (OFF_IE + SZ_IE)

// scratch inside the unified region (floats, relative to uni base)
#define SCR_SC 0                          // ROWS*N (sc, then intra in-place)
#define SCR_H  (SZ_IA)                    // ROWS*64
#define SCR_CORR (SCR_H + ROWS*64)        // ROWS*N raw clipped corr
#define SCR_DEG (SCR_CORR + SZ_IA)
#define SCR_CLUS (SCR_DEG + ROWS)
#define SCR_DENS (SCR_CLUS + ROWS)
#define SCR_STREN (SCR_DENS + BN)
#define SCR_GFV (SCR_STREN + BN)          // NB*150
#define SCR_AUX (SCR_GFV + NB*150)        // 2*NB

__device__ __forceinline__ float sigmoidf_(float x){ return 1.0f/(1.0f+expf(-x)); }
#define CLIP1(x) fminf(1.0f, fmaxf(-1.0f, (x)))

// ---------------- K1a: normalized corr -> global scratch ----------------
// LDS = 35.5 KB -> 4 blocks/CU (vs old fused kernel's 91.6 KB -> 1 block/CU)
__global__ __launch_bounds__(256) void k_corr(const float* __restrict__ band,
                                              float* __restrict__ corr_out)
{
    __shared__ float sx[NF*120];          // sx[f*120+n], normalized in place
    __shared__ float smu[120], srs[120];
    int bk = blockIdx.x;
    int b = bk >> 2, k = bk & 3;
    int t = threadIdx.x;
    const float* xin = band + ((size_t)b*NN_*NK + k)*NF;
    for (int e = t; e < NN_*NF; e += 256){
        int n = e / NF, f = e - n*NF;
        sx[f*120 + n] = xin[(size_t)n*NK*NF + f];
    }
    __syncthreads();
    if (t < NN_){
        float s = 0.f, ss = 0.f;
        for (int f = 0; f < NF; ++f){ float v = sx[f*120+t]; s += v; ss += v*v; }
        float mu = s * (1.0f/NF);
        float sd = sqrtf(fmaxf(ss - s*mu, 1e-8f));
        smu[t] = mu; srs[t] = 1.0f/sd;    // (+1e-8 on std product is ~1e-10 rel; folded)
    }
    __syncthreads();
    for (int e = t; e < NF*NN_; e += 256){
        int f = e / NN_, n = e - f*NN_;
        sx[f*120+n] = (sx[f*120+n] - smu[n]) * srs[n];
    }
    __syncthreads();
    float* dst = corr_out + (size_t)bk * NN2;
    for (int tt = t; tt < 29*29; tt += 256){
        int ti = tt / 29, tj = tt - ti*29;
        int i0 = ti*4, j0 = tj*4;
        float acc[4][4] = {};
        for (int f = 0; f < NF; ++f){
            const float4 a = *(const float4*)&sx[f*120 + i0];
            const float4 c = *(const float4*)&sx[f*120 + j0];
            float av[4] = {a.x,a.y,a.z,a.w};
            float cv[4] = {c.x,c.y,c.z,c.w};
            #pragma unroll
            for (int r = 0; r < 4; ++r)
                #pragma unroll
                for (int cc = 0; cc < 4; ++cc)
                    acc[r][cc] = fmaf(av[r], cv[cc], acc[r][cc]);
        }
        #pragma unroll
        for (int r = 0; r < 4; ++r){
            float4 v;
            v.x = CLIP1(acc[r][0]); v.y = CLIP1(acc[r][1]);
            v.z = CLIP1(acc[r][2]); v.w = CLIP1(acc[r][3]);
            *(float4*)&dst[(i0+r)*NN_ + j0] = v;
        }
    }
}

// ---------------- K1b: top-k + threshold + sym -> sc ----------------
// packed-key top-10: u = (bits(|c|) & ~0x7F) | (127 - j)  -> one u32 compare/level,
// exact lowest-index-first tie-break, 2 threads per row.
__global__ __launch_bounds__(256) void k_topk_mask(const float* __restrict__ corr_in,
    const float* __restrict__ thadj, float* __restrict__ sc_out)
{
    __shared__ float sc_[NN_*LROW];       // 54.3 KB, padded
    __shared__ unsigned skm[NN_*4];
    __shared__ unsigned stop[232*10];     // per-half sorted top-10
    int bk = blockIdx.x;
    int t = threadIdx.x;
    const float* src = corr_in + (size_t)bk*NN2;
    for (int e = t; e < NN2; e += 256){
        int i = e / NN_, j = e - i*NN_;
        sc_[i*LROW + j] = src[e];
    }
    __syncthreads();
    if (t < 232){
        int r = t >> 1, h = t & 1;
        const float* row = &sc_[r*LROW + h*58];
        int jbase = h*58;
        unsigned tv[TOPK];
        #pragma unroll
        for (int p = 0; p < TOPK; ++p) tv[p] = 0u;
        for (int jj = 0; jj < 58; ++jj){
            float c = fabsf(row[jj]);
            unsigned u = (__float_as_uint(c) & 0xFFFFFF80u) | (unsigned)(127 - (jbase + jj));
            #pragma unroll
            for (int p = 0; p < TOPK; ++p){
                unsigned old = tv[p];
                bool gt = u > old;
                tv[p] = gt ? u : old;
                u = gt ? old : u;
            }
        }
        #pragma unroll
        for (int p = 0; p < TOPK; ++p) stop[t*10 + p] = tv[p];
    }
    __syncthreads();
    if (t < NN_){
        const unsigned* A = &stop[(2*t)*10];
        const unsigned* Bp = &stop[(2*t+1)*10];
        int pa = 0, pb = 0;
        unsigned m0=0,m1=0,m2=0,m3=0;
        #pragma unroll
        for (int p = 0; p < TOPK; ++p){
            unsigned ua = A[pa], ub = Bp[pb];
            unsigned u;
            if (ua > ub){ u = ua; ++pa; } else { u = ub; ++pb; }
            int j = 127 - (int)(u & 127u);
            unsigned bit = 1u << (j & 31);
            int w = j >> 5;
            if (w == 0) m0 |= bit; else if (w == 1) m1 |= bit; else if (w == 2) m2 |= bit; else m3 |= bit;
        }
        skm[t*4+0]=m0; skm[t*4+1]=m1; skm[t*4+2]=m2; skm[t*4+3]=m3;
    }
    __syncthreads();
    float th = 0.1f + sigmoidf_(thadj[0]) * 0.2f;
    float* dst = sc_out + (size_t)bk * NN2;
    for (int e = t; e < NN2; e += 256){
        int i = e / NN_, j = e - i*NN_;
        float cij = sc_[i*LROW + j];
        float cji = sc_[j*LROW + i];
        bool kij = (skm[i*4 + (j>>5)] >> (j&31)) & 1u;
        bool kji = (skm[j*4 + (i>>5)] >> (i&31)) & 1u;
        float mij = (fabsf(cij) > th && kij) ? cij : 0.0f;
        float mji = (fabsf(cji) > th && kji) ? cji : 0.0f;
        dst[e] = fmaxf(0.5f*(mij+mji), 0.0f);
    }
}

// ---------------- K2a: H = relu(sc @ W1^T + b1) ----------------
#define RB2A 32
__global__ __launch_bounds__(256) void k_mlp1(const float* __restrict__ sc,
    const float* __restrict__ W1, const float* __restrict__ b1, float* __restrict__ H)
{
    __shared__ float sW[64*117];
    __shared__ float sb[64];
    __shared__ float srow[RB2A*NN_];
    int t = threadIdx.x;
    for (int e = t; e < 64*NN_; e += 256){ int o = e / NN_, j = e - o*NN_; sW[o*117+j] = W1[e]; }
    if (t < 64) sb[t] = b1[t];
    int r0 = blockIdx.x * RB2A;
    for (int e = t; e < RB2A*NN_; e += 256) srow[e] = sc[(size_t)r0*NN_ + e];
    __syncthreads();
    int o = t & 63, g = t >> 6;
    const float* rp = &srow[g*8*NN_];
    float acc[8] = {};
    for (int j = 0; j < NN_; ++j){
        float w = sW[o*117+j];
        #pragma unroll
        for (int m = 0; m < 8; ++m)
            acc[m] = fmaf(rp[m*NN_ + j], w, acc[m]);
    }
    float bo = sb[o];
    #pragma unroll
    for (int m = 0; m < 8; ++m)
        H[(size_t)(r0 + g*8 + m)*64 + o] = fmaxf(acc[m] + bo, 0.0f);
}

// ---------------- K2b: intra = sigmoid(H @ W2^T + b2), in-place over sc ----------------
#define RB2B 32
__global__ __launch_bounds__(256) void k_mlp2(const float* __restrict__ Hbuf,
    const float* __restrict__ W2, const float* __restrict__ b2, float* __restrict__ intra)
{
    __shared__ float sW[NN_*65];
    __shared__ float sb[NN_];
    __shared__ float sH[RB2B*64];
    int t = threadIdx.x;
    for (int e = t; e < NN_*64; e += 256){ int j = e >> 6, o = e & 63; sW[j*65+o] = W2[e]; }
    if (t < NN_) sb[t] = b2[t];
    int r0 = blockIdx.x * RB2B;
    for (int e = t; e < RB2B*64; e += 256) sH[e] = Hbuf[(size_t)r0*64 + e];
    __syncthreads();
    for (int task = t; task < NN_*8; task += 256){
        int rg = task / NN_, j = task - rg*NN_;
        float acc[4] = {};
        const float* hp = &sH[rg*4*64];
        for (int o = 0; o < 64; ++o){
            float w = sW[j*65+o];
            #pragma unroll
            for (int m = 0; m < 4; ++m)
                acc[m] = fmaf(hp[m*64 + o], w, acc[m]);
        }
        float bj = sb[j];
        #pragma unroll
        for (int m = 0; m < 4; ++m)
            intra[((size_t)r0 + rg*4 + m)*NN_ + j] = sigmoidf_(acc[m] + bj);
    }
}

// ---------------- K3: intra_adj = sym(intra); deg/clus ----------------
__global__ __launch_bounds__(256) void k_sym_intra(const float* __restrict__ intra,
    float* __restrict__ intra_adj, float* __restrict__ deg_out, float* __restrict__ clus_out)
{
    __shared__ float sm[NN_*LROW];        // padded -> conflict-free transpose
    int bk = blockIdx.x, t = threadIdx.x;
    const float* src = intra + (size_t)bk*NN2;
    for (int e = t; e < NN2; e += 256){
        int i = e / NN_, j = e - i*NN_;
        sm[i*LROW + j] = src[e];
    }
    __syncthreads();
    float* dst = intra_adj + (size_t)bk*NN2;
    for (int e = t; e < NN2; e += 256){
        int i = e / NN_, j = e - i*NN_;
        dst[e] = 0.5f*(sm[i*LROW + j] + sm[j*LROW + i]);
    }
    if (t < NN_){
        float tri = 0.f; int dg = 0;
        for (int j = 0; j < NN_; ++j){
            float v = 0.5f*(sm[t*LROW+j] + sm[j*LROW+t]);
            tri = fmaf(v, v, tri);
            dg += (v > 0.f) ? 1 : 0;
        }
        float d = (float)dg;
        deg_out[(size_t)bk*NN_ + t] = d;
        clus_out[(size_t)bk*NN_ + t] = tri / (d*d + 1e-8f);
    }
}

// ---------------- K4: inter branch, fully fused ----------------
__global__ __launch_bounds__(256) void k_inter(const float* __restrict__ band,
    const float* __restrict__ attn, const float* __restrict__ thadj2,
    const float* __restrict__ fwp,
    const float* __restrict__ W1, const float* __restrict__ b1,
    const float* __restrict__ W2, const float* __restrict__ b2,
    float* __restrict__ inter_out, float* __restrict__ dens_out, float* __restrict__ stren_out)
{
    __shared__ float sW1[128], sb1[32], sW2[128], sb2[4];
    __shared__ float sMat[256*4];
    int t = threadIdx.x;
    if (t < 128) sW1[t] = W1[t];
    if (t < 32) sb1[t] = b1[t];
    if (t >= 128 && t < 256) sW2[t-128] = W2[t-128];
    if (t < 4) sb2[t] = b2[t];
    __syncthreads();
    int l = t & 3;
    int il = t >> 2;
    size_t item = (size_t)blockIdx.x*64 + il;

    const float* xr = band + item*(NK*NF) + l*NF;
    float s=0,p0=0,p1=0,p2=0,p3=0;
    for (int f = 0; f < NF; ++f){
        float v = xr[f];
        float v1=__shfl_xor(v,1), v2=__shfl_xor(v,2), v3=__shfl_xor(v,3);
        s += v; p0=fmaf(v,v,p0); p1=fmaf(v,v1,p1); p2=fmaf(v,v2,p2); p3=fmaf(v,v3,p3);
    }
    float mu = s*(1.0f/NF);
    float mu1=__shfl_xor(mu,1), mu2=__shfl_xor(mu,2), mu3=__shfl_xor(mu,3);
    float sd = sqrtf(fmaxf(p0 - s*mu, 1e-8f));
    float sd1=__shfl_xor(sd,1), sd2=__shfl_xor(sd,2), sd3=__shfl_xor(sd,3);
    float c0 = CLIP1((p0 - (float)NF*mu*mu )/(sd*sd +1e-8f));
    float c1 = CLIP1((p1 - (float)NF*mu*mu1)/(sd*sd1+1e-8f));
    float c2 = CLIP1((p2 - (float)NF*mu*mu2)/(sd*sd2+1e-8f));
    float c3 = CLIP1((p3 - (float)NF*mu*mu3)/(sd*sd3+1e-8f));

    const float* ar = attn + item*(NS*NK) + l;
    float as=0,q0=0,q1=0,q2=0,q3=0;
    #pragma unroll
    for (int s8 = 0; s8 < NS; ++s8){
        float v = ar[s8*NK];
        float v1=__shfl_xor(v,1), v2=__shfl_xor(v,2), v3=__shfl_xor(v,3);
        as += v; q0=fmaf(v,v,q0); q1=fmaf(v,v1,q1); q2=fmaf(v,v2,q2); q3=fmaf(v,v3,q3);
    }
    float am = as*(1.0f/NS);
    float am1=__shfl_xor(am,1), am2=__shfl_xor(am,2), am3=__shfl_xor(am,3);
    float ad = sqrtf(fmaxf(q0 - as*am, 1e-8f));
    float ad1=__shfl_xor(ad,1), ad2=__shfl_xor(ad,2), ad3=__shfl_xor(ad,3);
    float a0 = CLIP1((q0 - (float)NS*am*am )/(ad*ad +1e-8f));
    float a1 = CLIP1((q1 - (float)NS*am*am1)/(ad*ad1+1e-8f));
    float a2 = CLIP1((q2 - (float)NS*am*am2)/(ad*ad2+1e-8f));
    float a3 = CLIP1((q3 - (float)NS*am*am3)/(ad*ad3+1e-8f));

    float fwv = sigmoidf_(fwp[0]);
    float g0 = fwv*c0 + (1.0f-fwv)*a0;
    float g1 = fwv*c1 + (1.0f-fwv)*a1;
    float g2 = fwv*c2 + (1.0f-fwv)*a2;
    float g3 = fwv*c3 + (1.0f-fwv)*a3;
    float th2 = 0.2f + sigmoidf_(thadj2[0])*0.2f;
    float m0 = (fabsf(g0)>th2)?g0:0.f;
    float m1 = (fabsf(g1)>th2)?g1:0.f;
    float m2 = (fabsf(g2)>th2)?g2:0.f;
    float m3 = (fabsf(g3)>th2)?g3:0.f;

    // write masked matrix row-major (cols via XOR slot), then symmetrize
    sMat[il*16 + l*4 + (l^0)] = m0;
    sMat[il*16 + l*4 + (l^1)] = m1;
    sMat[il*16 + l*4 + (l^2)] = m2;
    sMat[il*16 + l*4 + (l^3)] = m3;
    __syncthreads();
    float x0 = fmaxf(0.5f*(sMat[il*16 + l*4 + 0] + sMat[il*16 + 0*4 + l]), 0.f);
    float x1 = fmaxf(0.5f*(sMat[il*16 + l*4 + 1] + sMat[il*16 + 1*4 + l]), 0.f);
    float x2 = fmaxf(0.5f*(sMat[il*16 + l*4 + 2] + sMat[il*16 + 2*4 + l]), 0.f);
    float x3 = fmaxf(0.5f*(sMat[il*16 + l*4 + 3] + sMat[il*16 + 3*4 + l]), 0.f);

    float h[32];
    #pragma unroll
    for (int o = 0; o < 32; ++o){
        float acc = sb1[o];
        acc = fmaf(sW1[o*4+0], x0, acc);
        acc = fmaf(sW1[o*4+1], x1, acc);
        acc = fmaf(sW1[o*4+2], x2, acc);
        acc = fmaf(sW1[o*4+3], x3, acc);
        h[o] = fmaxf(acc, 0.f);
    }
    float o0=sb2[0], o1=sb2[1], o2=sb2[2], o3=sb2[3];
    #pragma unroll
    for (int o = 0; o < 32; ++o){
        float hv = h[o];
        o0 = fmaf(sW2[0*32+o], hv, o0);
        o1 = fmaf(sW2[1*32+o], hv, o1);
        o2 = fmaf(sW2[2*32+o], hv, o2);
        o3 = fmaf(sW2[3*32+o], hv, o3);
    }
    o0 = sigmoidf_(o0); o1 = sigmoidf_(o1); o2 = sigmoidf_(o2); o3 = sigmoidf_(o3);
    __syncthreads();
    sMat[il*16 + l*4 + 0] = o0;
    sMat[il*16 + l*4 + 1] = o1;
    sMat[il*16 + l*4 + 2] = o2;
    sMat[il*16 + l*4 + 3] = o3;
    __syncthreads();
    float y0 = 0.5f*(o0 + sMat[il*16 + 0*4 + l]);
    float y1 = 0.5f*(o1 + sMat[il*16 + 1*4 + l]);
    float y2 = 0.5f*(o2 + sMat[il*16 + 2*4 + l]);
    float y3 = 0.5f*(o3 + sMat[il*16 + 3*4 + l]);
    *(float4*)&inter_out[item*16 + l*4] = make_float4(y0,y1,y2,y3);

    float cnt = ((y0>0.f)?1.f:0.f) + ((y1>0.f)?1.f:0.f) + ((y2>0.f)?1.f:0.f) + ((y3>0.f)?1.f:0.f);
    float sum = y0+y1+y2+y3;
    cnt += __shfl_xor(cnt,1); cnt += __shfl_xor(cnt,2);
    sum += __shfl_xor(sum,1); sum += __shfl_xor(sum,2);
    if (l == 0){
        dens_out[item]  = cnt * (1.0f/16.0f);
        stren_out[item] = sum * (1.0f/16.0f);
    }
}

// ---------------- node features transpose-copy ----------------
__global__ __launch_bounds__(256) void k_nodefeat(const float* __restrict__ band, float* __restrict__ nf)
{
    const int total4 = NB*KN*NF/4;
    for (int x4 = blockIdx.x*blockDim.x + threadIdx.x; x4 < total4; x4 += gridDim.x*blockDim.x){
        int x = x4*4;
        int f = x % NF;
        int rest = x / NF;
        int n = rest % NN_;
        int rest2 = rest / NN_;
        int k = rest2 & 3;
        int b = rest2 >> 2;
        float4 v = *(const float4*)&band[(((size_t)b*NN_ + n)*NK + k)*NF + f];
        *(float4*)&nf[x] = v;
    }
}

// ---------------- per-(b,f) mean/std ----------------
__global__ __launch_bounds__(64) void k_meanstd(const float* __restrict__ band, float* __restrict__ gf)
{
    int bf = blockIdx.x; int b = bf / NF, f = bf - b*NF;
    int t = threadIdx.x;
    float s = 0.f, ss = 0.f;
    for (int nk = t; nk < NN_*NK; nk += 64){
        float v = band[(size_t)b*(NN_*NK*NF) + (size_t)nk*NF + f];
        s += v; ss += v*v;
    }
    #pragma unroll
    for (int d = 1; d < 64; d <<= 1){ s += __shfl_xor(s,d); ss += __shfl_xor(ss,d); }
    if (t == 0){
        const float M = (float)(NN_*NK);
        float mean = s / M;
        float var = fmaxf((ss - s*mean)/(M - 1.0f), 0.0f);
        gf[(size_t)b*150 + f] = mean;
        gf[(size_t)b*150 + NF + f] = sqrtf(var);
    }
}

// ---------------- per-b graph stats ----------------
__global__ __launch_bounds__(256) void k_graphstats(const float* __restrict__ deg,
    const float* __restrict__ clus, const float* __restrict__ dens,
    const float* __restrict__ stren, float* __restrict__ gf, float* __restrict__ aux)
{
    int b = blockIdx.x, t = threadIdx.x;
    __shared__ float sA[4], sB[4];

    float s = 0.f, ss = 0.f;
    for (int e = t; e < KN; e += 256){ float v = deg[(size_t)b*KN + e]; s += v; ss += v*v; }
    #pragma unroll
    for (int d = 1; d < 64; d <<= 1){ s += __shfl_xor(s,d); ss += __shfl_xor(ss,d); }
    if ((t & 63) == 0){ sA[t>>6] = s; sB[t>>6] = ss; }
    __syncthreads();
    if (t == 0){
        float S0 = sA[0]+sA[1]+sA[2]+sA[3], S1 = sB[0]+sB[1]+sB[2]+sB[3];
        float Mv = (float)KN, mean = S0/Mv;
        float var = fmaxf((S1 - S0*mean)/(Mv - 1.0f), 0.0f);
        gf[(size_t)b*150 + 144] = mean;
        gf[(size_t)b*150 + 145] = sqrtf(var);
        aux[b] = S0;
    }
    __syncthreads();

    s = 0.f; ss = 0.f;
    for (int e = t; e < KN; e += 256){ float v = clus[(size_t)b*KN + e]; s += v; ss += v*v; }
    #pragma unroll
    for (int d = 1; d < 64; d <<= 1){ s += __shfl_xor(s,d); ss += __shfl_xor(ss,d); }
    if ((t & 63) == 0){ sA[t>>6] = s; sB[t>>6] = ss; }
    __syncthreads();
    if (t == 0){
        float S0 = sA[0]+sA[1]+sA[2]+sA[3], S1 = sB[0]+sB[1]+sB[2]+sB[3];
        float Mv = (float)KN, mean = S0/Mv;
        float var = fmaxf((S1 - S0*mean)/(Mv - 1.0f), 0.0f);
        gf[(size_t)b*150 + 146] = mean;
        gf[(size_t)b*150 + 147] = sqrtf(var);
    }
    __syncthreads();

    s = 0.f; ss = 0.f;
    for (int e = t; e < NN_; e += 256){ s += dens[(size_t)b*NN_ + e]; ss += stren[(size_t)b*NN_ + e]; }
    #pragma unroll
    for (int d = 1; d < 64; d <<= 1){ s += __shfl_xor(s,d); ss += __shfl_xor(ss,d); }
    if ((t & 63) == 0){ sA[t>>6] = s; sB[t>>6] = ss; }
    __syncthreads();
    if (t == 0){
        float S0 = sA[0]+sA[1]+sA[2]+sA[3], S1 = sB[0]+sB[1]+sB[2]+sB[3];
        gf[(size_t)b*150 + 148] = S0 / (float)NN_;
        gf[(size_t)b*150 + 149] = S1 / (float)NN_;
        aux[128 + b] = S0 * 16.0f;
    }
}

// ---------------- graph linear ----------------
__global__ __launch_bounds__(256) void k_graphlin(const float* __restrict__ gf,
    const float* __restrict__ Wc, const float* __restrict__ bc, float* __restrict__ outp)
{
    int id = blockIdx.x*blockDim.x + threadIdx.x;
    if (id >= NB*128) return;
    int b = id >> 7, o = id & 127;
    float acc = bc[o];
    const float* g = gf + (size_t)b*150;
    const float* w = Wc + (size_t)o*150;
    for (int c = 0; c < 150; ++c) acc = fmaf(g[c], w[c], acc);
    outp[id] = fmaxf(acc, 0.f);
}

// ---------------- sparsity scalars ----------------
__global__ __launch_bounds__(128) void k_sparsity(const float* __restrict__ aux, float* __restrict__ out3)
{
    int t = threadIdx.x;
    float a = aux[t];
    float c = aux[128 + t];
    #pragma unroll
    for (int d = 1; d < 64; d <<= 1){ a += __shfl_xor(a,d); c += __shfl_xor(c,d); }
    __shared__ float sA[2], sC[2];
    if ((t & 63) == 0){ sA[t>>6] = a; sC[t>>6] = c; }
    __syncthreads();
    if (t == 0){
        float icnt = sA[0]+sA[1], jcnt = sC[0]+sC[1];
        const float it = 6889472.0f, jt = 237568.0f;
        float isp = 1.0f - icnt/it;
        float jsp = 1.0f - jcnt/jt;
        out3[0] = isp; out3[1] = jsp;
        out3[2] = (isp*it + jsp*jt)/(it + jt);
    }
}

// ---------------- unified assembly (runs LAST) ----------------
__global__ __launch_bounds__(128) void k_unified(const float* __restrict__ intra_adj,
    const float* __restrict__ inter_adj, float* __restrict__ uni)
{
    int row = blockIdx.x;                  // b*464 + p
    int b = row / KN, p = row - b*KN;
    int k1 = p / NN_, i = p - k1*NN_;
    int t = threadIdx.x;
    if (t >= NN_) return;
    int q0 = t*4;
    int k2 = t / 29;
    int j0 = q0 - k2*NN_;
    float4 v;
    if (k2 == k1){
        v = *(const float4*)&intra_adj[(((size_t)b*NK + k1)*NN_ + i)*NN_ + j0];
    } else {
        int d = i - j0;
        float val = 0.f;
        if (d >= 0 && d < 4)
            val = inter_adj[(((size_t)b*NN_ + i)*NK + k1)*NK + k2];
        v.x = (d==0)?val:0.f;
        v.y = (d==1)?val:0.f;
        v.z = (d==2)?val:0.f;
        v.w = (d==3)?val:0.f;
    }
    *(float4*)&uni[(size_t)row*KN + q0] = v;
}

extern "C" void kernel_launch(void* const* d_in, const int* in_sizes, int n_in,
                              void* d_out, int out_size, void* d_ws, size_t ws_size,
                              hipStream_t stream)
{
    const float* band = (const float*)d_in[0];
    const float* attn = (const float*)d_in[1];
    const float* thA  = (const float*)d_in[2];
    const float* thE  = (const float*)d_in[3];
    const float* fw   = (const float*)d_in[4];
    const float* iW1  = (const float*)d_in[5];
    const float* ib1  = (const float*)d_in[6];
    const float* iW2  = (const float*)d_in[7];
    const float* ib2  = (const float*)d_in[8];
    const float* eW1  = (const float*)d_in[9];
    const float* eb1  = (const float*)d_in[10];
    const float* eW2  = (const float*)d_in[11];
    const float* eb2  = (const float*)d_in[12];
    const float* cW   = (const float*)d_in[13];
    const float* cb   = (const float*)d_in[14];

    float* out = (float*)d_out;
    float* uni = out + OFF_UNI;
    float* nf  = out + OFF_NF;
    float* gfo = out + OFF_GF;
    float* ia  = out + OFF_IA;
    float* ie  = out + OFF_IE;
    float* sp  = out + OFF_SP;

    float* scr_sc    = uni + SCR_SC;
    float* scr_H     = uni + SCR_H;
    float* scr_corr  = uni + SCR_CORR;
    float* scr_deg   = uni + SCR_DEG;
    float* scr_clus  = uni + SCR_CLUS;
    float* scr_dens  = uni + SCR_DENS;
    float* scr_stren = uni + SCR_STREN;
    float* scr_gf    = uni + SCR_GFV;
    float* scr_aux   = uni + SCR_AUX;

    k_corr<<<BK, 256, 0, stream>>>(band, scr_corr);
    k_topk_mask<<<BK, 256, 0, stream>>>(scr_corr, thA, scr_sc);
    k_mlp1<<<ROWS/RB2A, 256, 0, stream>>>(scr_sc, iW1, ib1, scr_H);
    k_mlp2<<<ROWS/RB2B, 256, 0, stream>>>(scr_H, iW2, ib2, scr_sc);
    k_sym_intra<<<BK, 256, 0, stream>>>(scr_sc, ia, scr_deg, scr_clus);
    k_inter<<<BN/64, 256, 0, stream>>>(band, attn, thE, fw, eW1, eb1, eW2, eb2,
                                       ie, scr_dens, scr_stren);
    k_nodefeat<<<2048, 256, 0, stream>>>(band, nf);
    k_meanstd<<<NB*NF, 64, 0, stream>>>(band, scr_gf);
    k_graphstats<<<NB, 256, 0, stream>>>(scr_deg, scr_clus, scr_dens, scr_stren, scr_gf, scr_aux);
    k_graphlin<<<64, 256, 0, stream>>>(scr_gf, cW, cb, gfo);
    k_sparsity<<<1, 128, 0, stream>>>(scr_aux, sp);
    k_unified<<<NB*KN, 128, 0, stream>>>(ia, ie, uni);
}